// Round 3
// baseline (502.441 us; speedup 1.0000x reference)
//
#include <hip/hip_runtime.h>
#include <cstdint>
#include <cmath>

#define DIM   768
#define HID   3072
#define NEXP  8
#define DLOW  192
#define NPB   1024            // tokens per image (32*32)
#define NTOK  8192
#define KD    1536            // NEXP*DLOW
#define CHUNK 4096            // token chunk for shared-expert hidden

typedef unsigned short ushort_t;
typedef short   short8  __attribute__((ext_vector_type(8)));
typedef float   float4v __attribute__((ext_vector_type(4)));

__device__ inline ushort_t f2b(float f) {
    union { float f; unsigned int i; } v; v.f = f;
    unsigned int x = v.i;
    return (ushort_t)((x + 0x7fffu + ((x >> 16) & 1u)) >> 16);   // RNE
}
__device__ inline float b2f(ushort_t u) {
    union { unsigned int i; float f; } v; v.i = ((unsigned int)u) << 16; return v.f;
}
__device__ inline float gelu_exact(float v) {
    return 0.5f * v * (1.0f + erff(v * 0.70710678118654752440f));
}

// ---------------------------------------------------------------------------
// GEMM: acc[m,n] = sum_k A[m,k]*B[n,k]  (bf16 operands, k-contiguous rows)
// 128x128 tile, BK=32, 4 waves, mfma_f32_16x16x32_bf16.
// MODE 0: Cb[m,n]           = bf16(acc)                       (ld=N)
// MODE 1: Cb[m,n]           = bf16(gelu(acc + bias[n]))       (ld=N)
// MODE 2: Cf[b,col,nn](f32) = acc + bias[col] + X[b,col,nn]   (token=m_base+m)
// MODE 3: Cf[b,col,nn](f32) += acc                            (token=m_base+m)
// ---------------------------------------------------------------------------
template<int MODE>
__global__ __launch_bounds__(256)
void gemm_bt(const ushort_t* __restrict__ A, const ushort_t* __restrict__ B,
             ushort_t* __restrict__ Cb, float* __restrict__ Cf,
             const float* __restrict__ bias, const float* __restrict__ X,
             int N, int K, int m_base)
{
    __shared__ __align__(16) ushort_t As[128 * 32];
    __shared__ __align__(16) ushort_t Bs[128 * 32];

    const int tid  = threadIdx.x;
    const int lane = tid & 63;
    const int wave = tid >> 6;
    const int quad = lane >> 4;
    const int l16  = lane & 15;
    const int wm   = (wave >> 1) * 64;
    const int wn   = (wave & 1) * 64;
    const int m0   = blockIdx.y * 128;
    const int n0   = blockIdx.x * 128;

    float4v acc[4][4];
#pragma unroll
    for (int i = 0; i < 4; i++)
#pragma unroll
        for (int j = 0; j < 4; j++) acc[i][j] = (float4v)0.0f;

    const int f0 = tid, f1 = 256 + tid;
    const ushort_t* ga0 = A + (size_t)(m0 + (f0 >> 2)) * K + (f0 & 3) * 8;
    const ushort_t* ga1 = A + (size_t)(m0 + (f1 >> 2)) * K + (f1 & 3) * 8;
    const ushort_t* gb0 = B + (size_t)(n0 + (f0 >> 2)) * K + (f0 & 3) * 8;
    const ushort_t* gb1 = B + (size_t)(n0 + (f1 >> 2)) * K + (f1 & 3) * 8;

    for (int k0 = 0; k0 < K; k0 += 32) {
        uint4 a0 = *(const uint4*)(ga0 + k0);
        uint4 a1 = *(const uint4*)(ga1 + k0);
        uint4 b0 = *(const uint4*)(gb0 + k0);
        uint4 b1 = *(const uint4*)(gb1 + k0);
        __syncthreads();
        *(uint4*)&As[f0 * 8] = a0;  *(uint4*)&As[f1 * 8] = a1;
        *(uint4*)&Bs[f0 * 8] = b0;  *(uint4*)&Bs[f1 * 8] = b1;
        __syncthreads();

        short8 af[4], bv[4];
#pragma unroll
        for (int im = 0; im < 4; im++)
            af[im] = *(const short8*)&As[(wm + im * 16 + l16) * 32 + quad * 8];
#pragma unroll
        for (int in = 0; in < 4; in++)
            bv[in] = *(const short8*)&Bs[(wn + in * 16 + l16) * 32 + quad * 8];
#pragma unroll
        for (int im = 0; im < 4; im++)
#pragma unroll
            for (int in = 0; in < 4; in++)
                acc[im][in] = __builtin_amdgcn_mfma_f32_16x16x32_bf16(
                    af[im], bv[in], acc[im][in], 0, 0, 0);
    }

#pragma unroll
    for (int in = 0; in < 4; in++) {
        const int col = n0 + wn + in * 16 + l16;
        float bvv = 0.0f;
        if (MODE == 1 || MODE == 2) bvv = bias[col];
#pragma unroll
        for (int im = 0; im < 4; im++) {
            const int rowl = m0 + wm + im * 16 + quad * 4;
            if (MODE <= 1) {
#pragma unroll
                for (int r = 0; r < 4; r++) {
                    float v = acc[im][in][r] + bvv;
                    if (MODE == 1) v = gelu_exact(v);
                    Cb[(size_t)(rowl + r) * N + col] = f2b(v);
                }
            } else {
                const int grow = m_base + rowl;           // global token, %4==0
                const int bb = grow >> 10, nn = grow & 1023;
                const size_t base = ((size_t)bb * DIM + col) * NPB + nn;
                float4 v;
                v.x = acc[im][in][0]; v.y = acc[im][in][1];
                v.z = acc[im][in][2]; v.w = acc[im][in][3];
                if (MODE == 2) {
                    const float4 xv = *(const float4*)(X + base);
                    v.x += bvv + xv.x; v.y += bvv + xv.y;
                    v.z += bvv + xv.z; v.w += bvv + xv.w;
                } else {
                    const float4 ov = *(const float4*)(Cf + base);
                    v.x += ov.x; v.y += ov.y; v.z += ov.z; v.w += ov.w;
                }
                *(float4*)(Cf + base) = v;
            }
        }
    }
}

// ---------------------------------------------------------------------------
// x f32 [B,C,N] -> XTbf bf16 [T,C]
// ---------------------------------------------------------------------------
__global__ void transpose_x_cvt(const float* __restrict__ x, ushort_t* __restrict__ XT)
{
    __shared__ ushort_t tile[32][33];
    const int tx = threadIdx.x, ty = threadIdx.y;
    const int n0 = blockIdx.x * 32, c0 = blockIdx.y * 32, b = blockIdx.z;
#pragma unroll
    for (int j = 0; j < 4; j++)
        tile[ty + 8 * j][tx] = f2b(x[((size_t)b * DIM + c0 + ty + 8 * j) * NPB + n0 + tx]);
    __syncthreads();
#pragma unroll
    for (int j = 0; j < 4; j++)
        XT[((size_t)b * NPB + n0 + ty + 8 * j) * DIM + c0 + tx] = tile[tx][ty + 8 * j];
}

// w_up f32 [KD][DIM] -> WupTb bf16 [DIM][KD]
__global__ void transpose_wup_cvt(const float* __restrict__ src, ushort_t* __restrict__ dst)
{
    __shared__ ushort_t tile[32][33];
    const int tx = threadIdx.x, ty = threadIdx.y;
    const int c0 = blockIdx.x * 32, k0 = blockIdx.y * 32;
#pragma unroll
    for (int j = 0; j < 4; j++)
        tile[ty + 8 * j][tx] = f2b(src[(size_t)(k0 + ty + 8 * j) * DIM + c0 + tx]);
    __syncthreads();
#pragma unroll
    for (int j = 0; j < 4; j++)
        dst[(size_t)(c0 + ty + 8 * j) * KD + k0 + tx] = tile[tx][ty + 8 * j];
}

// f32 -> bf16 elementwise (count % 4 == 0), packed stores
__global__ void cvt_bf16(const float* __restrict__ src, ushort_t* __restrict__ dst, int count4)
{
    const int i = blockIdx.x * 256 + threadIdx.x;
    if (i >= count4) return;
    const float4 v = *(const float4*)(src + (size_t)i * 4);
    uint2 p;
    p.x = (unsigned)f2b(v.x) | ((unsigned)f2b(v.y) << 16);
    p.y = (unsigned)f2b(v.z) | ((unsigned)f2b(v.w) << 16);
    *(uint2*)(dst + (size_t)i * 4) = p;
}

// ---------------------------------------------------------------------------
// Weff[e][c] = sum_d w_down[e*192+d][c] * rw[d]   (all f32, exact fold)
// ---------------------------------------------------------------------------
__global__ __launch_bounds__(256)
void weff_kernel(const float* __restrict__ wdn, const float* __restrict__ rw,
                 float* __restrict__ Weff)
{
    const int idx = blockIdx.x * 256 + threadIdx.x;   // 0..6143
    const int e = idx / DIM, c = idx % DIM;
    float s = 0.0f;
    for (int d = 0; d < DLOW; d++)
        s += wdn[(size_t)(e * DLOW + d) * DIM + c] * rw[d];
    Weff[idx] = s;
}

// ---------------------------------------------------------------------------
// Router (all f32): thread t owns one token. logits -> softmax -> top2 -> aux
// ---------------------------------------------------------------------------
__global__ __launch_bounds__(256)
void router_kernel(const float* __restrict__ x, const float* __restrict__ Weff,
                   int* __restrict__ tokE, float* __restrict__ tokW,
                   float* __restrict__ accbuf)
{
    __shared__ float sW[NEXP * DIM];    // 24.6 KB
    __shared__ float sAcc[16];
    const int tid = threadIdx.x;
    for (int i = tid; i < NEXP * DIM; i += 256) sW[i] = Weff[i];
    if (tid < 16) sAcc[tid] = 0.0f;
    __syncthreads();

    const int t = blockIdx.x * 256 + tid;
    const int b = t >> 10, n = t & 1023;
    const float* xb = x + (size_t)b * DIM * NPB + n;

    float lg[8];
#pragma unroll
    for (int e = 0; e < 8; e++) lg[e] = 0.0f;
    for (int c = 0; c < DIM; c++) {
        const float xv = xb[(size_t)c * NPB];
#pragma unroll
        for (int e = 0; e < 8; e++) lg[e] += xv * sW[e * DIM + c];
    }

    float mx = lg[0];
#pragma unroll
    for (int e = 1; e < 8; e++) mx = fmaxf(mx, lg[e]);
    float pr[8], s = 0.0f;
#pragma unroll
    for (int e = 0; e < 8; e++) { pr[e] = expf(lg[e] - mx); s += pr[e]; }
    const float inv = 1.0f / s;
#pragma unroll
    for (int e = 0; e < 8; e++) pr[e] *= inv;
    int e0 = 0;
#pragma unroll
    for (int e = 1; e < 8; e++) if (pr[e] > pr[e0]) e0 = e;
    int e1 = (e0 == 0) ? 1 : 0;
#pragma unroll
    for (int e = 0; e < 8; e++) if (e != e0 && pr[e] > pr[e1]) e1 = e;
    const float wsum = pr[e0] + pr[e1];
    tokE[2 * t + 0] = e0;  tokE[2 * t + 1] = e1;
    tokW[2 * t + 0] = pr[e0] / wsum;  tokW[2 * t + 1] = pr[e1] / wsum;

#pragma unroll
    for (int e = 0; e < 8; e++) atomicAdd(&sAcc[e], pr[e]);
    atomicAdd(&sAcc[8 + e0], 1.0f);
    atomicAdd(&sAcc[8 + e1], 1.0f);
    __syncthreads();
    if (tid < 16) atomicAdd(&accbuf[tid], sAcc[tid]);
}

// ---------------------------------------------------------------------------
// In-place densify: FB[t,k] <- weight(t,k/192)*gelu(FB[t,k]); block0 -> aux
// ---------------------------------------------------------------------------
__global__ __launch_bounds__(256)
void actw_kernel(ushort_t* __restrict__ FB, const int* __restrict__ tokE,
                 const float* __restrict__ tokW, const float* __restrict__ accbuf,
                 float* __restrict__ outAux)
{
    const int t = blockIdx.x;
    const int e0 = tokE[2 * t], e1 = tokE[2 * t + 1];
    const float w0 = tokW[2 * t], w1 = tokW[2 * t + 1];
#pragma unroll
    for (int j = 0; j < 6; j++) {
        const int k = j * 256 + threadIdx.x;
        const int e = k / DLOW;
        const float f = b2f(FB[(size_t)t * KD + k]);
        const float m = (e == e0) ? w0 : ((e == e1) ? w1 : 0.0f);
        FB[(size_t)t * KD + k] = f2b(gelu_exact(f) * m);
    }
    if (blockIdx.x == 0 && threadIdx.x == 0) {
        float aux = 0.0f;
        for (int e = 0; e < 8; e++) aux += accbuf[e] * accbuf[8 + e];
        outAux[0] = aux * 8.0f / ((float)NTOK * (float)NTOK);
    }
}

// ---------------------------------------------------------------------------
extern "C" void kernel_launch(void* const* d_in, const int* in_sizes, int n_in,
                              void* d_out, int out_size, void* d_ws, size_t ws_size,
                              hipStream_t stream)
{
    (void)in_sizes; (void)n_in; (void)out_size; (void)ws_size;

    const float* x   = (const float*)d_in[0];
    const float* w1  = (const float*)d_in[1];
    const float* b1  = (const float*)d_in[2];
    const float* w2  = (const float*)d_in[3];
    const float* b2  = (const float*)d_in[4];
    const float* wdn = (const float*)d_in[5];
    const float* rw  = (const float*)d_in[6];
    const float* wup = (const float*)d_in[7];
    float* out = (float*)d_out;

    // workspace layout (~52 MB)
    char* ws = (char*)d_ws;
    size_t off = 0;
    ushort_t* XTbf  = (ushort_t*)(ws + off); off += (size_t)NTOK * DIM * 2;   // 12.6 MB
    ushort_t* w1b   = (ushort_t*)(ws + off); off += (size_t)HID * DIM * 2;    //  4.7 MB
    ushort_t* w2b   = (ushort_t*)(ws + off); off += (size_t)DIM * HID * 2;    //  4.7 MB
    ushort_t* wdnb  = (ushort_t*)(ws + off); off += (size_t)KD * DIM * 2;     //  2.4 MB
    ushort_t* WupTb = (ushort_t*)(ws + off); off += (size_t)DIM * KD * 2;     //  2.4 MB
    ushort_t* U     = (ushort_t*)(ws + off); off += (size_t)CHUNK * HID * 2;  // 25.2 MB (HT chunk / FB union)
    float*    Weff  = (float*)  (ws + off);  off += (size_t)NEXP * DIM * 4;
    int*      tokE  = (int*)    (ws + off);  off += (size_t)NTOK * 2 * 4;
    float*    tokW  = (float*)  (ws + off);  off += (size_t)NTOK * 2 * 4;
    float*    accb  = (float*)  (ws + off);  off += 256;
    ushort_t* FB = U;   // feats buffer reuses the HT-chunk region

    const dim3 tb(32, 8);
    transpose_x_cvt  <<<dim3(32, 24, 8), tb, 0, stream>>>(x, XTbf);
    transpose_wup_cvt<<<dim3(24, 48),    tb, 0, stream>>>(wup, WupTb);
    cvt_bf16<<<(HID * DIM / 4 + 255) / 256, 256, 0, stream>>>(w1, w1b, HID * DIM / 4);
    cvt_bf16<<<(DIM * HID / 4 + 255) / 256, 256, 0, stream>>>(w2, w2b, DIM * HID / 4);
    cvt_bf16<<<(KD * DIM / 4 + 255) / 256, 256, 0, stream>>>(wdn, wdnb, KD * DIM / 4);
    weff_kernel<<<NEXP * DIM / 256, 256, 0, stream>>>(wdn, rw, Weff);

    hipMemsetAsync(accb, 0, 64, stream);
    router_kernel<<<NTOK / 256, 256, 0, stream>>>(x, Weff, tokE, tokW, accb);

    // shared expert, 2 token-chunks: U = gelu(XT@w1^T+b1); out = U@w2^T+b2+x
    for (int c = 0; c < NTOK / CHUNK; c++) {
        gemm_bt<1><<<dim3(HID / 128, CHUNK / 128), 256, 0, stream>>>(
            XTbf + (size_t)c * CHUNK * DIM, w1b, U, nullptr, b1, nullptr, HID, DIM, 0);
        gemm_bt<2><<<dim3(DIM / 128, CHUNK / 128), 256, 0, stream>>>(
            U, w2b, nullptr, out, b2, x, DIM, HID, c * CHUNK);
    }

    // router feats: FB[t, e*192+d] = XT @ w_down^T   (overwrites U)
    gemm_bt<0><<<dim3(KD / 128, NTOK / 128), 256, 0, stream>>>(
        XTbf, wdnb, FB, nullptr, nullptr, nullptr, KD, DIM, 0);

    actw_kernel<<<NTOK, 256, 0, stream>>>(FB, tokE, tokW, accb, out + (size_t)NTOK * DIM);

    // AoE: out += AW @ WupT^T
    gemm_bt<3><<<dim3(DIM / 128, NTOK / 128), 256, 0, stream>>>(
        FB, WupTb, nullptr, out, nullptr, nullptr, DIM, KD, 0);
}

// Round 4
// 436.123 us; speedup vs baseline: 1.1521x; 1.1521x over previous
//
#include <hip/hip_runtime.h>
#include <cstdint>
#include <cmath>

#define DIM   768
#define HID   3072
#define NEXP  8
#define DLOW  192
#define NPB   1024            // tokens per image (32*32)
#define NTOK  8192
#define KD    1536            // NEXP*DLOW

typedef unsigned short ushort_t;
typedef short   short8  __attribute__((ext_vector_type(8)));
typedef float   float4v __attribute__((ext_vector_type(4)));

__device__ inline ushort_t f2b(float f) {
    union { float f; unsigned int i; } v; v.f = f;
    unsigned int x = v.i;
    return (ushort_t)((x + 0x7fffu + ((x >> 16) & 1u)) >> 16);   // RNE
}
__device__ inline float b2f(ushort_t u) {
    union { unsigned int i; float f; } v; v.i = ((unsigned int)u) << 16; return v.f;
}
__device__ inline float gelu_exact(float v) {
    return 0.5f * v * (1.0f + erff(v * 0.70710678118654752440f));
}

// async global->LDS, 16 B per lane (global_load_lds_dwordx4)
__device__ __forceinline__ void async_ld16(const ushort_t* g, ushort_t* l) {
    __builtin_amdgcn_global_load_lds(
        (const __attribute__((address_space(1))) void*)g,
        (__attribute__((address_space(3))) void*)l,
        16, 0, 0);
}

// ---------------------------------------------------------------------------
// GEMM: acc[m,n] = sum_k A[m,k]*B[n,k]  (bf16 operands, k-contiguous rows)
// 128x128 tile, BK=32, 4 waves, mfma_f32_16x16x32_bf16, async LDS staging.
// MODE 0: Cb[m,n]           = bf16(acc)                       (ld=N)
// MODE 1: Cb[m,n]           = bf16(gelu(acc + bias[n]))       (ld=N)
// MODE 2: Cf[b,col,nn](f32) = acc + bias[col] + X[b,col,nn]   (token=m_base+m)
// MODE 3: Cf[b,col,nn](f32) += acc                            (token=m_base+m)
// ---------------------------------------------------------------------------
template<int MODE>
__global__ __launch_bounds__(256)
void gemm_bt(const ushort_t* __restrict__ A, const ushort_t* __restrict__ B,
             ushort_t* __restrict__ Cb, float* __restrict__ Cf,
             const float* __restrict__ bias, const float* __restrict__ X,
             int N, int K, int m_base)
{
    __shared__ __align__(16) ushort_t As[128 * 32];
    __shared__ __align__(16) ushort_t Bs[128 * 32];

    const int tid  = threadIdx.x;
    const int lane = tid & 63;
    const int wave = tid >> 6;
    const int quad = lane >> 4;
    const int l16  = lane & 15;
    const int wm   = (wave >> 1) * 64;
    const int wn   = (wave & 1) * 64;
    const int m0   = blockIdx.y * 128;
    const int n0   = blockIdx.x * 128;

    float4v acc[4][4];
#pragma unroll
    for (int i = 0; i < 4; i++)
#pragma unroll
        for (int j = 0; j < 4; j++) acc[i][j] = (float4v)0.0f;

    const int f0 = tid, f1 = 256 + tid;
    const ushort_t* ga0 = A + (size_t)(m0 + (f0 >> 2)) * K + (f0 & 3) * 8;
    const ushort_t* ga1 = A + (size_t)(m0 + (f1 >> 2)) * K + (f1 & 3) * 8;
    const ushort_t* gb0 = B + (size_t)(n0 + (f0 >> 2)) * K + (f0 & 3) * 8;
    const ushort_t* gb1 = B + (size_t)(n0 + (f1 >> 2)) * K + (f1 & 3) * 8;
    ushort_t* la0 = &As[f0 * 8];
    ushort_t* la1 = &As[f1 * 8];
    ushort_t* lb0 = &Bs[f0 * 8];
    ushort_t* lb1 = &Bs[f1 * 8];

    for (int k0 = 0; k0 < K; k0 += 32) {
        __syncthreads();                  // prior iter's ds_reads complete
        async_ld16(ga0 + k0, la0);
        async_ld16(ga1 + k0, la1);
        async_ld16(gb0 + k0, lb0);
        async_ld16(gb1 + k0, lb1);
        __syncthreads();                  // drains vmcnt -> staged data visible

        short8 af[4], bv[4];
#pragma unroll
        for (int im = 0; im < 4; im++)
            af[im] = *(const short8*)&As[(wm + im * 16 + l16) * 32 + quad * 8];
#pragma unroll
        for (int in = 0; in < 4; in++)
            bv[in] = *(const short8*)&Bs[(wn + in * 16 + l16) * 32 + quad * 8];
#pragma unroll
        for (int im = 0; im < 4; im++)
#pragma unroll
            for (int in = 0; in < 4; in++)
                acc[im][in] = __builtin_amdgcn_mfma_f32_16x16x32_bf16(
                    af[im], bv[in], acc[im][in], 0, 0, 0);
    }

#pragma unroll
    for (int in = 0; in < 4; in++) {
        const int col = n0 + wn + in * 16 + l16;
        float bvv = 0.0f;
        if (MODE == 1 || MODE == 2) bvv = bias[col];
#pragma unroll
        for (int im = 0; im < 4; im++) {
            const int rowl = m0 + wm + im * 16 + quad * 4;
            if (MODE <= 1) {
#pragma unroll
                for (int r = 0; r < 4; r++) {
                    float v = acc[im][in][r] + bvv;
                    if (MODE == 1) v = gelu_exact(v);
                    Cb[(size_t)(rowl + r) * N + col] = f2b(v);
                }
            } else {
                const int grow = m_base + rowl;           // global token, %4==0
                const int bb = grow >> 10, nn = grow & 1023;
                const size_t base = ((size_t)bb * DIM + col) * NPB + nn;
                float4 v;
                v.x = acc[im][in][0]; v.y = acc[im][in][1];
                v.z = acc[im][in][2]; v.w = acc[im][in][3];
                if (MODE == 2) {
                    const float4 xv = *(const float4*)(X + base);
                    v.x += bvv + xv.x; v.y += bvv + xv.y;
                    v.z += bvv + xv.z; v.w += bvv + xv.w;
                } else {
                    const float4 ov = *(const float4*)(Cf + base);
                    v.x += ov.x; v.y += ov.y; v.z += ov.z; v.w += ov.w;
                }
                *(float4*)(Cf + base) = v;
            }
        }
    }
}

// ---------------------------------------------------------------------------
// x f32 [B,C,N] -> XTbf bf16 [T,C]
// ---------------------------------------------------------------------------
__global__ void transpose_x_cvt(const float* __restrict__ x, ushort_t* __restrict__ XT)
{
    __shared__ ushort_t tile[32][33];
    const int tx = threadIdx.x, ty = threadIdx.y;
    const int n0 = blockIdx.x * 32, c0 = blockIdx.y * 32, b = blockIdx.z;
#pragma unroll
    for (int j = 0; j < 4; j++)
        tile[ty + 8 * j][tx] = f2b(x[((size_t)b * DIM + c0 + ty + 8 * j) * NPB + n0 + tx]);
    __syncthreads();
#pragma unroll
    for (int j = 0; j < 4; j++)
        XT[((size_t)b * NPB + n0 + ty + 8 * j) * DIM + c0 + tx] = tile[tx][ty + 8 * j];
}

// w_up f32 [KD][DIM] -> WupTb bf16 [DIM][KD]
__global__ void transpose_wup_cvt(const float* __restrict__ src, ushort_t* __restrict__ dst)
{
    __shared__ ushort_t tile[32][33];
    const int tx = threadIdx.x, ty = threadIdx.y;
    const int c0 = blockIdx.x * 32, k0 = blockIdx.y * 32;
#pragma unroll
    for (int j = 0; j < 4; j++)
        tile[ty + 8 * j][tx] = f2b(src[(size_t)(k0 + ty + 8 * j) * DIM + c0 + tx]);
    __syncthreads();
#pragma unroll
    for (int j = 0; j < 4; j++)
        dst[(size_t)(c0 + ty + 8 * j) * KD + k0 + tx] = tile[tx][ty + 8 * j];
}

// f32 -> bf16 elementwise (count % 4 == 0), packed stores
__global__ void cvt_bf16(const float* __restrict__ src, ushort_t* __restrict__ dst, int count4)
{
    const int i = blockIdx.x * 256 + threadIdx.x;
    if (i >= count4) return;
    const float4 v = *(const float4*)(src + (size_t)i * 4);
    uint2 p;
    p.x = (unsigned)f2b(v.x) | ((unsigned)f2b(v.y) << 16);
    p.y = (unsigned)f2b(v.z) | ((unsigned)f2b(v.w) << 16);
    *(uint2*)(dst + (size_t)i * 4) = p;
}

// ---------------------------------------------------------------------------
// Weff[e][c] = sum_d w_down[e*192+d][c] * rw[d]   (all f32, exact fold)
// ---------------------------------------------------------------------------
__global__ __launch_bounds__(256)
void weff_kernel(const float* __restrict__ wdn, const float* __restrict__ rw,
                 float* __restrict__ Weff)
{
    const int idx = blockIdx.x * 256 + threadIdx.x;   // 0..6143
    const int e = idx / DIM, c = idx % DIM;
    float s = 0.0f;
    for (int d = 0; d < DLOW; d++)
        s += wdn[(size_t)(e * DLOW + d) * DIM + c] * rw[d];
    Weff[idx] = s;
}

// ---------------------------------------------------------------------------
// Router (all f32): thread t owns one token. logits -> softmax -> top2 -> aux
// ---------------------------------------------------------------------------
__global__ __launch_bounds__(256)
void router_kernel(const float* __restrict__ x, const float* __restrict__ Weff,
                   int* __restrict__ tokE, float* __restrict__ tokW,
                   float* __restrict__ accbuf)
{
    __shared__ float sW[NEXP * DIM];    // 24.6 KB
    __shared__ float sAcc[16];
    const int tid = threadIdx.x;
    for (int i = tid; i < NEXP * DIM; i += 256) sW[i] = Weff[i];
    if (tid < 16) sAcc[tid] = 0.0f;
    __syncthreads();

    const int t = blockIdx.x * 256 + tid;
    const int b = t >> 10, n = t & 1023;
    const float* xb = x + (size_t)b * DIM * NPB + n;

    float lg[8];
#pragma unroll
    for (int e = 0; e < 8; e++) lg[e] = 0.0f;
    for (int c = 0; c < DIM; c++) {
        const float xv = xb[(size_t)c * NPB];
#pragma unroll
        for (int e = 0; e < 8; e++) lg[e] += xv * sW[e * DIM + c];
    }

    float mx = lg[0];
#pragma unroll
    for (int e = 1; e < 8; e++) mx = fmaxf(mx, lg[e]);
    float pr[8], s = 0.0f;
#pragma unroll
    for (int e = 0; e < 8; e++) { pr[e] = expf(lg[e] - mx); s += pr[e]; }
    const float inv = 1.0f / s;
#pragma unroll
    for (int e = 0; e < 8; e++) pr[e] *= inv;
    int e0 = 0;
#pragma unroll
    for (int e = 1; e < 8; e++) if (pr[e] > pr[e0]) e0 = e;
    int e1 = (e0 == 0) ? 1 : 0;
#pragma unroll
    for (int e = 0; e < 8; e++) if (e != e0 && pr[e] > pr[e1]) e1 = e;
    const float wsum = pr[e0] + pr[e1];
    tokE[2 * t + 0] = e0;  tokE[2 * t + 1] = e1;
    tokW[2 * t + 0] = pr[e0] / wsum;  tokW[2 * t + 1] = pr[e1] / wsum;

#pragma unroll
    for (int e = 0; e < 8; e++) atomicAdd(&sAcc[e], pr[e]);
    atomicAdd(&sAcc[8 + e0], 1.0f);
    atomicAdd(&sAcc[8 + e1], 1.0f);
    __syncthreads();
    if (tid < 16) atomicAdd(&accbuf[tid], sAcc[tid]);
}

// ---------------------------------------------------------------------------
// In-place densify: FB[t,k] <- weight(t,k/192)*gelu(FB[t,k]); block0 -> aux
// ---------------------------------------------------------------------------
__global__ __launch_bounds__(256)
void actw_kernel(ushort_t* __restrict__ FB, const int* __restrict__ tokE,
                 const float* __restrict__ tokW, const float* __restrict__ accbuf,
                 float* __restrict__ outAux)
{
    const int t = blockIdx.x;
    const int e0 = tokE[2 * t], e1 = tokE[2 * t + 1];
    const float w0 = tokW[2 * t], w1 = tokW[2 * t + 1];
#pragma unroll
    for (int j = 0; j < 6; j++) {
        const int k = j * 256 + threadIdx.x;
        const int e = k / DLOW;
        const float f = b2f(FB[(size_t)t * KD + k]);
        const float m = (e == e0) ? w0 : ((e == e1) ? w1 : 0.0f);
        FB[(size_t)t * KD + k] = f2b(gelu_exact(f) * m);
    }
    if (blockIdx.x == 0 && threadIdx.x == 0) {
        float aux = 0.0f;
        for (int e = 0; e < 8; e++) aux += accbuf[e] * accbuf[8 + e];
        outAux[0] = aux * 8.0f / ((float)NTOK * (float)NTOK);
    }
}

// ---------------------------------------------------------------------------
extern "C" void kernel_launch(void* const* d_in, const int* in_sizes, int n_in,
                              void* d_out, int out_size, void* d_ws, size_t ws_size,
                              hipStream_t stream)
{
    (void)in_sizes; (void)n_in; (void)out_size;

    const float* x   = (const float*)d_in[0];
    const float* w1  = (const float*)d_in[1];
    const float* b1  = (const float*)d_in[2];
    const float* w2  = (const float*)d_in[3];
    const float* b2  = (const float*)d_in[4];
    const float* wdn = (const float*)d_in[5];
    const float* rw  = (const float*)d_in[6];
    const float* wup = (const float*)d_in[7];
    float* out = (float*)d_out;

    // fixed workspace pieces
    const size_t fixed = (size_t)NTOK * DIM * 2      // XTbf
                       + (size_t)HID * DIM * 2       // w1b
                       + (size_t)DIM * HID * 2       // w2b
                       + (size_t)KD * DIM * 2        // wdnb
                       + (size_t)DIM * KD * 2        // WupTb
                       + (size_t)NEXP * DIM * 4      // Weff
                       + (size_t)NTOK * 2 * 4        // tokE
                       + (size_t)NTOK * 2 * 4        // tokW
                       + 256;                        // accb
    // pick largest token-chunk that fits the workspace (graph-safe: pure fn of ws_size)
    const int chunk = (ws_size >= fixed + (size_t)NTOK * HID * 2) ? NTOK : NTOK / 2;

    char* ws = (char*)d_ws;
    size_t off = 0;
    ushort_t* XTbf  = (ushort_t*)(ws + off); off += (size_t)NTOK * DIM * 2;
    ushort_t* w1b   = (ushort_t*)(ws + off); off += (size_t)HID * DIM * 2;
    ushort_t* w2b   = (ushort_t*)(ws + off); off += (size_t)DIM * HID * 2;
    ushort_t* wdnb  = (ushort_t*)(ws + off); off += (size_t)KD * DIM * 2;
    ushort_t* WupTb = (ushort_t*)(ws + off); off += (size_t)DIM * KD * 2;
    float*    Weff  = (float*)  (ws + off);  off += (size_t)NEXP * DIM * 4;
    int*      tokE  = (int*)    (ws + off);  off += (size_t)NTOK * 2 * 4;
    float*    tokW  = (float*)  (ws + off);  off += (size_t)NTOK * 2 * 4;
    float*    accb  = (float*)  (ws + off);  off += 256;
    ushort_t* U     = (ushort_t*)(ws + off); // chunk*HID bf16
    ushort_t* FB    = U;                     // feats reuses U (disjoint lifetime)

    const dim3 tb(32, 8);
    transpose_x_cvt  <<<dim3(32, 24, 8), tb, 0, stream>>>(x, XTbf);
    transpose_wup_cvt<<<dim3(24, 48),    tb, 0, stream>>>(wup, WupTb);
    cvt_bf16<<<(HID * DIM / 4 + 255) / 256, 256, 0, stream>>>(w1, w1b, HID * DIM / 4);
    cvt_bf16<<<(DIM * HID / 4 + 255) / 256, 256, 0, stream>>>(w2, w2b, DIM * HID / 4);
    cvt_bf16<<<(KD * DIM / 4 + 255) / 256, 256, 0, stream>>>(wdn, wdnb, KD * DIM / 4);
    weff_kernel<<<NEXP * DIM / 256, 256, 0, stream>>>(wdn, rw, Weff);

    hipMemsetAsync(accb, 0, 64, stream);
    router_kernel<<<NTOK / 256, 256, 0, stream>>>(x, Weff, tokE, tokW, accb);

    // shared expert: U = gelu(XT@w1^T+b1); out = U@w2^T + b2 + x
    for (int c = 0; c < NTOK / chunk; c++) {
        gemm_bt<1><<<dim3(HID / 128, chunk / 128), 256, 0, stream>>>(
            XTbf + (size_t)c * chunk * DIM, w1b, U, nullptr, b1, nullptr, HID, DIM, 0);
        gemm_bt<2><<<dim3(DIM / 128, chunk / 128), 256, 0, stream>>>(
            U, w2b, nullptr, out, b2, x, DIM, HID, c * chunk);
    }

    // router feats: FB[t, e*192+d] = XT @ w_down^T   (overwrites U)
    gemm_bt<0><<<dim3(KD / 128, NTOK / 128), 256, 0, stream>>>(
        XTbf, wdnb, FB, nullptr, nullptr, nullptr, KD, DIM, 0);

    actw_kernel<<<NTOK, 256, 0, stream>>>(FB, tokE, tokW, accb, out + (size_t)NTOK * DIM);

    // AoE: out += AW @ WupT^T
    gemm_bt<3><<<dim3(DIM / 128, NTOK / 128), 256, 0, stream>>>(
        FB, WupTb, nullptr, out, nullptr, nullptr, DIM, KD, 0);
}